// Round 2
// baseline (588.124 us; speedup 1.0000x reference)
//
#include <hip/hip_runtime.h>
#include <hip/hip_bf16.h>

#define NB   8
#define NTOK 1024
#define DDIM 1024
#define NEXP 16
#define HDIM 4096
#define CAP  80
#define BK   64
#define LDA  (BK + 8)

using bf16x8 = __attribute__((ext_vector_type(8))) __bf16;
using bf16x4 = __attribute__((ext_vector_type(4))) __bf16;
using f32x4  = __attribute__((ext_vector_type(4))) float;

// ---------------- X pre-convert: rows 0..79 of each b -> bf16 ----------------
__global__ __launch_bounds__(256) void xpre(const float* __restrict__ X,
                                            __bf16* __restrict__ Xb16)
{
    int idx = blockIdx.x * 256 + threadIdx.x;       // over 8*80*256 float4s
    int b   = idx / (CAP * 256);
    int rem = idx % (CAP * 256);
    int m   = rem >> 8, c = rem & 255;
    float4 v = *(const float4*)&X[((size_t)b * NTOK + m) * DDIM + c * 4];
    bf16x4 p = {(__bf16)v.x, (__bf16)v.y, (__bf16)v.z, (__bf16)v.w};
    *(bf16x4*)&Xb16[((size_t)b * CAP + m) * DDIM + c * 4] = p;
}

// ---------------- W pre-swizzle into MFMA-fragment-ordered bf16 panels -------
// P[e][nb][kt][wv][lane][8] bf16, 16B per lane -> GEMM reads ONE contiguous
// bf16x8 per (kt,wave). value = W[e][kt*32+(l>>4)*8+j][nb*64+wv*16+(l&15)].
// Block = (hc, ks, e), 512 thr; register 8x4 transpose; both sides coalesced.
// Only experts present in Y are converted.
__global__ __launch_bounds__(512) void wpre(const float* __restrict__ W,
                                            const int* __restrict__ Y,
                                            __bf16* __restrict__ P,
                                            int K, int H, int NB_, int KT_)
{
    const int e = blockIdx.z;
    bool used = false;
    #pragma unroll
    for (int i = 0; i < NB; ++i) used |= ((Y[i] & (NEXP - 1)) == e);
    if (!used) return;

    const int ks  = blockIdx.y;            // k-tile of 32 rows
    const int hc  = blockIdx.x;            // 512-col chunk
    const int t   = threadIdx.x;
    const int q3  = t >> 7;                // which 8-k chunk (0..3)
    const int h0g = t & 127;               // 4-col group within chunk
    const int hg  = hc * 512 + h0g * 4;
    const int k0  = ks * 32 + q3 * 8;

    const float* Ws = W + (size_t)e * K * H;
    float4 v[8];
    #pragma unroll
    for (int j = 0; j < 8; ++j)
        v[j] = *(const float4*)&Ws[(size_t)(k0 + j) * H + hg];   // 2KB contiguous / 128 lanes

    bf16x8 o0, o1, o2, o3;
    #pragma unroll
    for (int j = 0; j < 8; ++j) {
        o0[j] = (__bf16)v[j].x; o1[j] = (__bf16)v[j].y;
        o2[j] = (__bf16)v[j].z; o3[j] = (__bf16)v[j].w;
    }

    const int nb = hg >> 6, wv = (hg >> 4) & 3, l0 = q3 * 16 + (hg & 15);
    __bf16* dst = P + ((((size_t)(e * NB_ + nb) * KT_ + ks) * 4 + wv) * 64 + l0) * 8;
    *(bf16x8*)&dst[0]  = o0;   // i=0..3 -> l0+i : 64B contiguous per thread,
    *(bf16x8*)&dst[8]  = o1;   // fully contiguous across threads
    *(bf16x8*)&dst[16] = o2;
    *(bf16x8*)&dst[24] = o3;
}

// ---------------- GEMM1 + exact GELU (no LDS, no barriers) ----------------
__global__ __launch_bounds__(256) void moe_g1(
    const __bf16* __restrict__ Xb16, const int* __restrict__ Y,
    const __bf16* __restrict__ P1, __bf16* __restrict__ Hid)
{
    const int b  = blockIdx.y;
    const int e  = Y[b] & (NEXP - 1);
    const int tid = threadIdx.x;
    const int w  = tid >> 6, l = tid & 63, q = l >> 4, r = l & 15;
    const int n  = blockIdx.x * 64 + w * 16 + r;

    const __bf16* Xb  = Xb16 + (size_t)b * CAP * DDIM;
    const __bf16* pan = P1 + (size_t)(e * 64 + blockIdx.x) * 32 * 2048
                           + (size_t)w * 512 + (size_t)l * 8;

    f32x4 acc[5];
    #pragma unroll
    for (int i = 0; i < 5; ++i) acc[i] = f32x4{0.f, 0.f, 0.f, 0.f};

    #pragma unroll 4
    for (int t = 0; t < 32; ++t) {                     // k-tiles of 32
        bf16x8 bf = *(const bf16x8*)&pan[(size_t)t * 2048];   // contiguous stream
        #pragma unroll
        for (int mt = 0; mt < 5; ++mt) {
            bf16x8 af = *(const bf16x8*)&Xb[(size_t)(mt * 16 + r) * DDIM + t * 32 + q * 8];
            acc[mt] = __builtin_amdgcn_mfma_f32_16x16x32_bf16(af, bf, acc[mt], 0, 0, 0);
        }
    }

    __bf16* Hb = Hid + (size_t)b * CAP * HDIM;
    #pragma unroll
    for (int mt = 0; mt < 5; ++mt)
        #pragma unroll
        for (int v = 0; v < 4; ++v) {
            int m = mt * 16 + q * 4 + v;
            float x = acc[mt][v];
            float g = 0.5f * x * (1.0f + erff(x * 0.70710678118654752f));
            Hb[(size_t)m * HDIM + n] = (__bf16)g;
        }
}

// ---------------- GEMM2 (no LDS, no barriers; split-K=4 atomics) ----------------
__global__ __launch_bounds__(256) void moe_g2(
    const __bf16* __restrict__ Hid, const int* __restrict__ Y,
    const __bf16* __restrict__ P2, float* __restrict__ Out)
{
    const int b  = blockIdx.y;
    const int e  = Y[b] & (NEXP - 1);
    const int tid = threadIdx.x;
    const int w  = tid >> 6, l = tid & 63, q = l >> 4, r = l & 15;
    const int n  = blockIdx.x * 64 + w * 16 + r;
    const int kz = blockIdx.z * (HDIM / 4);

    const __bf16* Hb  = Hid + (size_t)b * CAP * HDIM;
    const __bf16* pan = P2 + (size_t)(e * 16 + blockIdx.x) * 128 * 2048
                           + (size_t)(blockIdx.z * 32) * 2048
                           + (size_t)w * 512 + (size_t)l * 8;

    f32x4 acc[5];
    #pragma unroll
    for (int i = 0; i < 5; ++i) acc[i] = f32x4{0.f, 0.f, 0.f, 0.f};

    #pragma unroll 4
    for (int t = 0; t < 32; ++t) {
        bf16x8 bf = *(const bf16x8*)&pan[(size_t)t * 2048];
        #pragma unroll
        for (int mt = 0; mt < 5; ++mt) {
            bf16x8 af = *(const bf16x8*)&Hb[(size_t)(mt * 16 + r) * HDIM + kz + t * 32 + q * 8];
            acc[mt] = __builtin_amdgcn_mfma_f32_16x16x32_bf16(af, bf, acc[mt], 0, 0, 0);
        }
    }

    float* Ob = Out + (size_t)b * NTOK * DDIM;
    #pragma unroll
    for (int mt = 0; mt < 5; ++mt)
        #pragma unroll
        for (int v = 0; v < 4; ++v) {
            int m = mt * 16 + q * 4 + v;
            atomicAdd(&Ob[(size_t)m * DDIM + n], acc[mt][v]);
        }
}

// ================= FALLBACK PATH (R1-proven, W fp32 direct) =================
__global__ __launch_bounds__(256) void moe_g1_fb(
    const float* __restrict__ X, const int* __restrict__ Y,
    const float* __restrict__ W1, __bf16* __restrict__ Hid)
{
    const int b = blockIdx.y, e = Y[b] & (NEXP - 1), nbase = blockIdx.x * 64;
    const int tid = threadIdx.x, w = tid >> 6, l = tid & 63, q = l >> 4, r = l & 15;
    const int n = nbase + w * 16 + r;
    const int kb = tid & 15, hb = tid >> 4, arow = tid >> 4, akg = tid & 15;
    __shared__ __bf16 As[2][CAP][LDA];
    __shared__ __bf16 Bt[2][64][LDA];
    const float* Xb = X + (size_t)b * NTOK * DDIM;
    const float* W1e = W1 + (size_t)e * DDIM * HDIM;
    f32x4 acc[5];
    #pragma unroll
    for (int i = 0; i < 5; ++i) acc[i] = f32x4{0.f, 0.f, 0.f, 0.f};
    float4 a_reg[5]; float4 b_reg[4];
    #pragma unroll
    for (int it = 0; it < 5; ++it)
        a_reg[it] = *(const float4*)&Xb[(size_t)(arow + 16 * it) * DDIM + akg * 4];
    #pragma unroll
    for (int kk = 0; kk < 4; ++kk)
        b_reg[kk] = *(const float4*)&W1e[(size_t)(kb * 4 + kk) * HDIM + nbase + hb * 4];
    int cur = 0;
    for (int t = 0; t < DDIM / BK; ++t) {
        #pragma unroll
        for (int it = 0; it < 5; ++it) {
            float4 v = a_reg[it];
            bf16x4 p = {(__bf16)v.x, (__bf16)v.y, (__bf16)v.z, (__bf16)v.w};
            *(bf16x4*)&As[cur][arow + 16 * it][akg * 4] = p;
        }
        {
            bf16x4 p0 = {(__bf16)b_reg[0].x, (__bf16)b_reg[1].x, (__bf16)b_reg[2].x, (__bf16)b_reg[3].x};
            bf16x4 p1 = {(__bf16)b_reg[0].y, (__bf16)b_reg[1].y, (__bf16)b_reg[2].y, (__bf16)b_reg[3].y};
            bf16x4 p2 = {(__bf16)b_reg[0].z, (__bf16)b_reg[1].z, (__bf16)b_reg[2].z, (__bf16)b_reg[3].z};
            bf16x4 p3 = {(__bf16)b_reg[0].w, (__bf16)b_reg[1].w, (__bf16)b_reg[2].w, (__bf16)b_reg[3].w};
            *(bf16x4*)&Bt[cur][hb * 4 + 0][kb * 4] = p0;
            *(bf16x4*)&Bt[cur][hb * 4 + 1][kb * 4] = p1;
            *(bf16x4*)&Bt[cur][hb * 4 + 2][kb * 4] = p2;
            *(bf16x4*)&Bt[cur][hb * 4 + 3][kb * 4] = p3;
        }
        __syncthreads();
        if (t + 1 < DDIM / BK) {
            const int k0 = (t + 1) * BK;
            #pragma unroll
            for (int it = 0; it < 5; ++it)
                a_reg[it] = *(const float4*)&Xb[(size_t)(arow + 16 * it) * DDIM + k0 + akg * 4];
            #pragma unroll
            for (int kk = 0; kk < 4; ++kk)
                b_reg[kk] = *(const float4*)&W1e[(size_t)(k0 + kb * 4 + kk) * HDIM + nbase + hb * 4];
        }
        #pragma unroll
        for (int s = 0; s < 2; ++s) {
            bf16x8 bf = *(const bf16x8*)&Bt[cur][w * 16 + r][s * 32 + q * 8];
            #pragma unroll
            for (int mt = 0; mt < 5; ++mt) {
                bf16x8 af = *(const bf16x8*)&As[cur][mt * 16 + r][s * 32 + q * 8];
                acc[mt] = __builtin_amdgcn_mfma_f32_16x16x32_bf16(af, bf, acc[mt], 0, 0, 0);
            }
        }
        cur ^= 1;
    }
    __bf16* Hb = Hid + (size_t)b * CAP * HDIM;
    #pragma unroll
    for (int mt = 0; mt < 5; ++mt)
        #pragma unroll
        for (int v = 0; v < 4; ++v) {
            int m = mt * 16 + q * 4 + v;
            float x = acc[mt][v];
            float g = 0.5f * x * (1.0f + erff(x * 0.70710678118654752f));
            Hb[(size_t)m * HDIM + n] = (__bf16)g;
        }
}

__global__ __launch_bounds__(256) void moe_g2_fb(
    const __bf16* __restrict__ Hid, const int* __restrict__ Y,
    const float* __restrict__ W2, float* __restrict__ Out)
{
    const int b = blockIdx.y, e = Y[b] & (NEXP - 1), nbase = blockIdx.x * 64;
    const int kz = blockIdx.z * (HDIM / 4);
    const int tid = threadIdx.x, w = tid >> 6, l = tid & 63, q = l >> 4, r = l & 15;
    const int n = nbase + w * 16 + r;
    const int kb = tid & 15, hb = tid >> 4, arow = tid >> 4, akg = tid & 15;
    __shared__ __bf16 As[2][CAP][LDA];
    __shared__ __bf16 Bt[2][64][LDA];
    const __bf16* Hb = Hid + (size_t)b * CAP * HDIM;
    const float* W2e = W2 + (size_t)e * HDIM * DDIM;
    f32x4 acc[5];
    #pragma unroll
    for (int i = 0; i < 5; ++i) acc[i] = f32x4{0.f, 0.f, 0.f, 0.f};
    uint2 a_reg[5]; float4 b_reg[4];
    #pragma unroll
    for (int it = 0; it < 5; ++it)
        a_reg[it] = *(const uint2*)&Hb[(size_t)(arow + 16 * it) * HDIM + kz + akg * 4];
    #pragma unroll
    for (int kk = 0; kk < 4; ++kk)
        b_reg[kk] = *(const float4*)&W2e[(size_t)(kz + kb * 4 + kk) * DDIM + nbase + hb * 4];
    int cur = 0;
    for (int t = 0; t < (HDIM / 4) / BK; ++t) {
        #pragma unroll
        for (int it = 0; it < 5; ++it)
            *(uint2*)&As[cur][arow + 16 * it][akg * 4] = a_reg[it];
        {
            bf16x4 p0 = {(__bf16)b_reg[0].x, (__bf16)b_reg[1].x, (__bf16)b_reg[2].x, (__bf16)b_reg[3].x};
            bf16x4 p1 = {(__bf16)b_reg[0].y, (__bf16)b_reg[1].y, (__bf16)b_reg[2].y, (__bf16)b_reg[3].y};
            bf16x4 p2 = {(__bf16)b_reg[0].z, (__bf16)b_reg[1].z, (__bf16)b_reg[2].z, (__bf16)b_reg[3].z};
            bf16x4 p3 = {(__bf16)b_reg[0].w, (__bf16)b_reg[1].w, (__bf16)b_reg[2].w, (__bf16)b_reg[3].w};
            *(bf16x4*)&Bt[cur][hb * 4 + 0][kb * 4] = p0;
            *(bf16x4*)&Bt[cur][hb * 4 + 1][kb * 4] = p1;
            *(bf16x4*)&Bt[cur][hb * 4 + 2][kb * 4] = p2;
            *(bf16x4*)&Bt[cur][hb * 4 + 3][kb * 4] = p3;
        }
        __syncthreads();
        if (t + 1 < (HDIM / 4) / BK) {
            const int k0 = kz + (t + 1) * BK;
            #pragma unroll
            for (int it = 0; it < 5; ++it)
                a_reg[it] = *(const uint2*)&Hb[(size_t)(arow + 16 * it) * HDIM + k0 + akg * 4];
            #pragma unroll
            for (int kk = 0; kk < 4; ++kk)
                b_reg[kk] = *(const float4*)&W2e[(size_t)(k0 + kb * 4 + kk) * DDIM + nbase + hb * 4];
        }
        #pragma unroll
        for (int s = 0; s < 2; ++s) {
            bf16x8 bf = *(const bf16x8*)&Bt[cur][w * 16 + r][s * 32 + q * 8];
            #pragma unroll
            for (int mt = 0; mt < 5; ++mt) {
                bf16x8 af = *(const bf16x8*)&As[cur][mt * 16 + r][s * 32 + q * 8];
                acc[mt] = __builtin_amdgcn_mfma_f32_16x16x32_bf16(af, bf, acc[mt], 0, 0, 0);
            }
        }
        cur ^= 1;
    }
    float* Ob = Out + (size_t)b * NTOK * DDIM;
    #pragma unroll
    for (int mt = 0; mt < 5; ++mt)
        #pragma unroll
        for (int v = 0; v < 4; ++v) {
            int m = mt * 16 + q * 4 + v;
            atomicAdd(&Ob[(size_t)m * DDIM + n], acc[mt][v]);
        }
}

extern "C" void kernel_launch(void* const* d_in, const int* in_sizes, int n_in,
                              void* d_out, int out_size, void* d_ws, size_t ws_size,
                              hipStream_t stream) {
    const float* X  = (const float*)d_in[0];
    const int*   Y  = (const int*)d_in[1];
    const float* W1 = (const float*)d_in[2];
    const float* W2 = (const float*)d_in[3];
    float* Out = (float*)d_out;

    // ws layout: Hid @0 (5.25 MB) | Xbf @6MiB (1.31 MB) | P1 @16MiB (128 MiB)
    //            | P2 @144MiB (128 MiB)  -> needs 272 MiB
    uint8_t* ws = (uint8_t*)d_ws;
    __bf16* Hid  = (__bf16*)ws;
    __bf16* Xb16 = (__bf16*)(ws + (6u  << 20));
    __bf16* P1   = (__bf16*)(ws + (16u << 20));
    __bf16* P2   = (__bf16*)(ws + (144u << 20));

    hipMemsetAsync(d_out, 0, (size_t)out_size * sizeof(float), stream);

    if (ws_size >= (size_t)(272u << 20)) {
        xpre<<<dim3(NB * CAP * 256 / 256), 256, 0, stream>>>(X, Xb16);
        wpre<<<dim3(8, 32, 16),  512, 0, stream>>>(W1, Y, P1, DDIM, HDIM, 64, 32);
        wpre<<<dim3(2, 128, 16), 512, 0, stream>>>(W2, Y, P2, HDIM, DDIM, 16, 128);
        moe_g1<<<dim3(HDIM / 64, NB),    256, 0, stream>>>(Xb16, Y, P1, Hid);
        moe_g2<<<dim3(DDIM / 64, NB, 4), 256, 0, stream>>>(Hid, Y, P2, Out);
    } else {
        moe_g1_fb<<<dim3(HDIM / 64, NB),    256, 0, stream>>>(X, Y, W1, Hid);
        moe_g2_fb<<<dim3(DDIM / 64, NB, 4), 256, 0, stream>>>(Hid, Y, W2, Out);
    }
}

// Round 3
// 491.968 us; speedup vs baseline: 1.1955x; 1.1955x over previous
//
#include <hip/hip_runtime.h>
#include <hip/hip_bf16.h>

#define NB   8
#define NTOK 1024
#define DDIM 1024
#define NEXP 16
#define HDIM 4096
#define CAP  80
#define BK   64
#define BN   128
#define LDA  (BK + 8)

using bf16x8 = __attribute__((ext_vector_type(8))) __bf16;
using bf16x4 = __attribute__((ext_vector_type(4))) __bf16;
using f32x4  = __attribute__((ext_vector_type(4))) float;

// ---------------- GEMM1, K-split z=2, fp32 partials ----------------
// Hpart[z][b][m][h] = sum_{k in z-slice} X[b][m][k] * W1[e][k][h]
// 512 thr = 8 waves, BN=128 (one 16-col tile per wave), M=80 (5 m-tiles).
// W rows read 512B contiguous per block visit (2 cache lines x2 vs BN=64).
__global__ __launch_bounds__(512) void moe_g1(
    const float* __restrict__ X, const int* __restrict__ Y,
    const float* __restrict__ W1, float* __restrict__ Hpart)
{
    const int b     = blockIdx.y;
    const int e     = Y[b] & (NEXP - 1);
    const int nbase = blockIdx.x * BN;
    const int kz    = blockIdx.z * 512;          // z in {0,1}
    const int tid   = threadIdx.x;
    const int w     = tid >> 6;                  // wave 0..7
    const int l     = tid & 63;
    const int q     = l >> 4;
    const int r     = l & 15;
    const int n     = nbase + w * 16 + r;
    const int kb    = tid & 15;                  // B-stage k-quad
    const int hb    = tid >> 4;                  // B-stage col-quad 0..31

    __shared__ __bf16 As[2][CAP][LDA];           // 23.0 KB
    __shared__ __bf16 Bt[2][BN][LDA];            // 36.9 KB (transposed W tile)

    const float* Xb  = X  + (size_t)b * NTOK * DDIM;
    const float* W1e = W1 + (size_t)e * DDIM * HDIM;

    f32x4 acc[5];
    #pragma unroll
    for (int i = 0; i < 5; ++i) acc[i] = f32x4{0.f, 0.f, 0.f, 0.f};

    float4 a_reg[3];                             // 80*16 quads = 1280 = 512*2.5
    float4 b_reg[4];

    // ---- prologue: tile 0
    #pragma unroll
    for (int it = 0; it < 3; ++it) {
        int idx = tid + 512 * it;
        if (it < 2 || idx < CAP * 16) {
            int row = idx >> 4, kg = idx & 15;
            a_reg[it] = *(const float4*)&Xb[(size_t)row * DDIM + kz + kg * 4];
        }
    }
    #pragma unroll
    for (int kk = 0; kk < 4; ++kk)
        b_reg[kk] = *(const float4*)&W1e[(size_t)(kz + kb * 4 + kk) * HDIM + nbase + hb * 4];

    int cur = 0;
    for (int t = 0; t < 8; ++t) {
        // ---- stage tile t
        #pragma unroll
        for (int it = 0; it < 3; ++it) {
            int idx = tid + 512 * it;
            if (it < 2 || idx < CAP * 16) {
                int row = idx >> 4, kg = idx & 15;
                float4 v = a_reg[it];
                bf16x4 p = {(__bf16)v.x, (__bf16)v.y, (__bf16)v.z, (__bf16)v.w};
                *(bf16x4*)&As[cur][row][kg * 4] = p;
            }
        }
        {   // 4x4 register transpose into Bt[h][k]
            bf16x4 p0 = {(__bf16)b_reg[0].x, (__bf16)b_reg[1].x, (__bf16)b_reg[2].x, (__bf16)b_reg[3].x};
            bf16x4 p1 = {(__bf16)b_reg[0].y, (__bf16)b_reg[1].y, (__bf16)b_reg[2].y, (__bf16)b_reg[3].y};
            bf16x4 p2 = {(__bf16)b_reg[0].z, (__bf16)b_reg[1].z, (__bf16)b_reg[2].z, (__bf16)b_reg[3].z};
            bf16x4 p3 = {(__bf16)b_reg[0].w, (__bf16)b_reg[1].w, (__bf16)b_reg[2].w, (__bf16)b_reg[3].w};
            *(bf16x4*)&Bt[cur][hb * 4 + 0][kb * 4] = p0;
            *(bf16x4*)&Bt[cur][hb * 4 + 1][kb * 4] = p1;
            *(bf16x4*)&Bt[cur][hb * 4 + 2][kb * 4] = p2;
            *(bf16x4*)&Bt[cur][hb * 4 + 3][kb * 4] = p3;
        }
        __syncthreads();

        // ---- prefetch tile t+1
        if (t + 1 < 8) {
            const int k0 = kz + (t + 1) * BK;
            #pragma unroll
            for (int it = 0; it < 3; ++it) {
                int idx = tid + 512 * it;
                if (it < 2 || idx < CAP * 16) {
                    int row = idx >> 4, kg = idx & 15;
                    a_reg[it] = *(const float4*)&Xb[(size_t)row * DDIM + k0 + kg * 4];
                }
            }
            #pragma unroll
            for (int kk = 0; kk < 4; ++kk)
                b_reg[kk] = *(const float4*)&W1e[(size_t)(k0 + kb * 4 + kk) * HDIM + nbase + hb * 4];
        }

        // ---- MFMA
        #pragma unroll
        for (int s = 0; s < 2; ++s) {
            bf16x8 bf = *(const bf16x8*)&Bt[cur][w * 16 + r][s * 32 + q * 8];
            #pragma unroll
            for (int mt = 0; mt < 5; ++mt) {
                bf16x8 af = *(const bf16x8*)&As[cur][mt * 16 + r][s * 32 + q * 8];
                acc[mt] = __builtin_amdgcn_mfma_f32_16x16x32_bf16(af, bf, acc[mt], 0, 0, 0);
            }
        }
        cur ^= 1;
    }

    // ---- plain fp32 stores to this z-slice's partial buffer
    float* Hp = Hpart + ((size_t)blockIdx.z * NB + b) * CAP * HDIM;
    #pragma unroll
    for (int mt = 0; mt < 5; ++mt)
        #pragma unroll
        for (int v = 0; v < 4; ++v) {
            int m = mt * 16 + q * 4 + v;
            Hp[(size_t)m * HDIM + n] = acc[mt][v];
        }
}

// ---------------- reduce z + exact GELU + cvt bf16 ----------------
__global__ __launch_bounds__(256) void gelu_red(const float* __restrict__ Hpart,
                                                __bf16* __restrict__ Hid)
{
    size_t i4 = (size_t)blockIdx.x * 256 + threadIdx.x;   // over 8*80*4096/4
    const size_t SL = (size_t)NB * CAP * HDIM;
    float4 v0 = *(const float4*)&Hpart[i4 * 4];
    float4 v1 = *(const float4*)&Hpart[SL + i4 * 4];
    float s[4] = {v0.x + v1.x, v0.y + v1.y, v0.z + v1.z, v0.w + v1.w};
    bf16x4 p;
    #pragma unroll
    for (int j = 0; j < 4; ++j) {
        float x = s[j];
        p[j] = (__bf16)(0.5f * x * (1.0f + erff(x * 0.70710678118654752f)));
    }
    *(bf16x4*)&Hid[i4 * 4] = p;
}

// ---------------- GEMM2, K-split z=8, fp32 partials ----------------
__global__ __launch_bounds__(512) void moe_g2(
    const __bf16* __restrict__ Hid, const int* __restrict__ Y,
    const float* __restrict__ W2, float* __restrict__ Opart)
{
    const int b     = blockIdx.y;
    const int e     = Y[b] & (NEXP - 1);
    const int nbase = blockIdx.x * BN;
    const int kz    = blockIdx.z * 512;          // z in 0..7
    const int tid   = threadIdx.x;
    const int w     = tid >> 6;
    const int l     = tid & 63;
    const int q     = l >> 4;
    const int r     = l & 15;
    const int n     = nbase + w * 16 + r;
    const int kb    = tid & 15;
    const int hb    = tid >> 4;

    __shared__ __bf16 As[2][CAP][LDA];
    __shared__ __bf16 Bt[2][BN][LDA];

    const __bf16* Hb  = Hid + (size_t)b * CAP * HDIM;
    const float*  W2e = W2  + (size_t)e * HDIM * DDIM;

    f32x4 acc[5];
    #pragma unroll
    for (int i = 0; i < 5; ++i) acc[i] = f32x4{0.f, 0.f, 0.f, 0.f};

    uint2  a_reg[3];
    float4 b_reg[4];

    #pragma unroll
    for (int it = 0; it < 3; ++it) {
        int idx = tid + 512 * it;
        if (it < 2 || idx < CAP * 16) {
            int row = idx >> 4, kg = idx & 15;
            a_reg[it] = *(const uint2*)&Hb[(size_t)row * HDIM + kz + kg * 4];
        }
    }
    #pragma unroll
    for (int kk = 0; kk < 4; ++kk)
        b_reg[kk] = *(const float4*)&W2e[(size_t)(kz + kb * 4 + kk) * DDIM + nbase + hb * 4];

    int cur = 0;
    for (int t = 0; t < 8; ++t) {
        #pragma unroll
        for (int it = 0; it < 3; ++it) {
            int idx = tid + 512 * it;
            if (it < 2 || idx < CAP * 16) {
                int row = idx >> 4, kg = idx & 15;
                *(uint2*)&As[cur][row][kg * 4] = a_reg[it];
            }
        }
        {
            bf16x4 p0 = {(__bf16)b_reg[0].x, (__bf16)b_reg[1].x, (__bf16)b_reg[2].x, (__bf16)b_reg[3].x};
            bf16x4 p1 = {(__bf16)b_reg[0].y, (__bf16)b_reg[1].y, (__bf16)b_reg[2].y, (__bf16)b_reg[3].y};
            bf16x4 p2 = {(__bf16)b_reg[0].z, (__bf16)b_reg[1].z, (__bf16)b_reg[2].z, (__bf16)b_reg[3].z};
            bf16x4 p3 = {(__bf16)b_reg[0].w, (__bf16)b_reg[1].w, (__bf16)b_reg[2].w, (__bf16)b_reg[3].w};
            *(bf16x4*)&Bt[cur][hb * 4 + 0][kb * 4] = p0;
            *(bf16x4*)&Bt[cur][hb * 4 + 1][kb * 4] = p1;
            *(bf16x4*)&Bt[cur][hb * 4 + 2][kb * 4] = p2;
            *(bf16x4*)&Bt[cur][hb * 4 + 3][kb * 4] = p3;
        }
        __syncthreads();

        if (t + 1 < 8) {
            const int k0 = kz + (t + 1) * BK;
            #pragma unroll
            for (int it = 0; it < 3; ++it) {
                int idx = tid + 512 * it;
                if (it < 2 || idx < CAP * 16) {
                    int row = idx >> 4, kg = idx & 15;
                    a_reg[it] = *(const uint2*)&Hb[(size_t)row * HDIM + k0 + kg * 4];
                }
            }
            #pragma unroll
            for (int kk = 0; kk < 4; ++kk)
                b_reg[kk] = *(const float4*)&W2e[(size_t)(k0 + kb * 4 + kk) * DDIM + nbase + hb * 4];
        }

        #pragma unroll
        for (int s = 0; s < 2; ++s) {
            bf16x8 bf = *(const bf16x8*)&Bt[cur][w * 16 + r][s * 32 + q * 8];
            #pragma unroll
            for (int mt = 0; mt < 5; ++mt) {
                bf16x8 af = *(const bf16x8*)&As[cur][mt * 16 + r][s * 32 + q * 8];
                acc[mt] = __builtin_amdgcn_mfma_f32_16x16x32_bf16(af, bf, acc[mt], 0, 0, 0);
            }
        }
        cur ^= 1;
    }

    float* Op = Opart + ((size_t)blockIdx.z * NB + b) * CAP * DDIM;
    #pragma unroll
    for (int mt = 0; mt < 5; ++mt)
        #pragma unroll
        for (int v = 0; v < 4; ++v) {
            int m = mt * 16 + q * 4 + v;
            Op[(size_t)m * DDIM + n] = acc[mt][v];
        }
}

// ---------------- reduce z=8 -> Out (rows m<80; rest stays memset 0) -------
__global__ __launch_bounds__(256) void out_red(const float* __restrict__ Opart,
                                               float* __restrict__ Out)
{
    size_t i4 = (size_t)blockIdx.x * 256 + threadIdx.x;   // over 8*80*1024/4
    const size_t SL = (size_t)NB * CAP * DDIM;
    float4 s = *(const float4*)&Opart[i4 * 4];
    #pragma unroll
    for (int z = 1; z < 8; ++z) {
        float4 v = *(const float4*)&Opart[(size_t)z * SL + i4 * 4];
        s.x += v.x; s.y += v.y; s.z += v.z; s.w += v.w;
    }
    size_t i = i4 * 4;                    // flat (b, m, d)
    size_t b = i / ((size_t)CAP * DDIM);
    size_t rem = i % ((size_t)CAP * DDIM);
    size_t m = rem / DDIM, d = rem % DDIM;
    *(float4*)&Out[(b * NTOK + m) * DDIM + d] = s;
}

extern "C" void kernel_launch(void* const* d_in, const int* in_sizes, int n_in,
                              void* d_out, int out_size, void* d_ws, size_t ws_size,
                              hipStream_t stream) {
    const float* X  = (const float*)d_in[0];
    const int*   Y  = (const int*)d_in[1];
    const float* W1 = (const float*)d_in[2];
    const float* W2 = (const float*)d_in[3];
    float* Out = (float*)d_out;

    // ws: Hid bf16 @0 (5.25 MB) | Hpart @8MiB (21 MB, z=2) | Opart @32MiB (21 MB, z=8)
    uint8_t* ws = (uint8_t*)d_ws;
    __bf16* Hid   = (__bf16*)ws;
    float*  Hpart = (float*)(ws + (8u  << 20));
    float*  Opart = (float*)(ws + (32u << 20));

    // rows n >= CAP of Out must be exactly zero.
    hipMemsetAsync(d_out, 0, (size_t)out_size * sizeof(float), stream);

    moe_g1<<<dim3(HDIM / BN, NB, 2), 512, 0, stream>>>(X, Y, W1, Hpart);
    gelu_red<<<dim3(NB * CAP * HDIM / 4 / 256), 256, 0, stream>>>(Hpart, Hid);
    moe_g2<<<dim3(DDIM / BN, NB, 8), 512, 0, stream>>>(Hid, Y, W2, Opart);
    out_red<<<dim3(NB * CAP * DDIM / 4 / 256), 256, 0, stream>>>(Opart, Out);
}